// Round 4
// baseline (229.449 us; speedup 1.0000x reference)
//
#include <hip/hip_runtime.h>

#define LSEQ 384
#define NROWS 1536      // B*L
#define FDIM 640
#define HDIM 128
#define PART 196608     // 1536*128

// ws layout (float indices)
#define WS_H1P 0                 // 4 x PART (H1 split-K partials)
#define WS_FIP (4*PART)          // 4 x PART
#define WS_FJP (8*PART)          // 4 x PART
#define WS_FI  (12*PART)         // final fi
#define WS_FJ  (13*PART)         // final fj
#define WS_QC  (14*PART)
#define WS_FLAG (WS_QC + NROWS)  // int[1536]
#define WS_CTR  (WS_FLAG + NROWS) // int[144] ticket counters (memset to 0 pre-launch)

// out layout (float indices)
#define OUT_PC    0
#define OUT_TC    4608
#define OUT_NET   9216
#define OUT_POT   10752
#define OUT_MASK  12288
#define OUT_EN    602112

typedef float f4 __attribute__((ext_vector_type(4)));

__device__ __forceinline__ void gl16(const float* g, float* l) {
    __builtin_amdgcn_global_load_lds((const __attribute__((address_space(1))) float*)g,
                                     (__attribute__((address_space(3))) float*)l, 16, 0, 0);
}

// ===== Kernel 1: split-K=4 GEMM (round-3 core) + last-block reduce/epilogue =====
// grid (48, 12): bx = m-tile (32 rows); by: mat = by>>2 (0=H1,1=fi,2=fj), kz = by&3.
// After writing partials, each block tickets ctr[mat*48+bx]; the 4th arrival
// (any dispatch order — no spin) performs the reduction for this (mat, m-tile):
//   mat 1/2: collapse 4 partials -> WS_FI/WS_FJ
//   mat 0:   collapse + bias/relu/BN + W2(readlane) + W3 + softmax + outputs
__global__ __launch_bounds__(256) void k_gemm(const float* __restrict__ X,
                                              const float* __restrict__ W1,
                                              const float* __restrict__ sW1,
                                              const float* __restrict__ b1,
                                              const float* __restrict__ gam,
                                              const float* __restrict__ bet,
                                              const float* __restrict__ rmean,
                                              const float* __restrict__ rvar,
                                              const float* __restrict__ W2,
                                              const float* __restrict__ b2,
                                              const float* __restrict__ W3,
                                              const float* __restrict__ b3,
                                              const int* __restrict__ seq,
                                              float* __restrict__ ws,
                                              float* __restrict__ out) {
    __shared__ __align__(16) float As[2][32][36];    // [buf][k][m] pad 36
    __shared__ __align__(16) float Bs[2][32][128];   // [buf][k][n]
    __shared__ int s_old;

    const int t = threadIdx.x;
    if (blockIdx.x == 0 && blockIdx.y == 0 && t < 4)
        out[OUT_EN + t] = 0.0f;        // energy zero (k2 atomicAdds later)

    const int m0 = blockIdx.x * 32;
    const int by = blockIdx.y;
    const int mat = by >> 2, kz = by & 3;
    const float* W = (mat == 0) ? W1 : (mat == 1 ? sW1 : sW1 + FDIM * HDIM);
    float* O = ws + (mat == 0 ? WS_H1P : (mat == 1 ? WS_FIP : WS_FJP)) + kz * PART;
    const int k0 = kz * 160;            // 5 iterations of BK=32

    const int lane = t & 63, wv = t >> 6;
    const int rg = t >> 5;              // 0..7 : row group (4 rows)
    const int cg = t & 31;              // 0..31: col group (4 cols)
    const int ar = t >> 3, ac4 = (t & 7) * 4;   // A stage: row 0..31, col4 0..28

    auto stage_B = [&](int buf, int kk) {
        const float* src = W + (long)kk * HDIM;
        float* dst = &Bs[buf][0][0];
#pragma unroll
        for (int i = 0; i < 4; i++) {
            const int c = wv * 4 + i;               // wave-uniform chunk id
            gl16(src + c * 256 + lane * 4, dst + c * 256);
        }
    };

    f4 acc[4];
    acc[0] = acc[1] = acc[2] = acc[3] = (f4){0.f, 0.f, 0.f, 0.f};

    stage_B(0, k0);
    {
        f4 av = *(const f4*)&X[(long)(m0 + ar) * FDIM + k0 + ac4];
        As[0][ac4 + 0][ar] = av[0];
        As[0][ac4 + 1][ar] = av[1];
        As[0][ac4 + 2][ar] = av[2];
        As[0][ac4 + 3][ar] = av[3];
    }
    __syncthreads();

    for (int kt = 0; kt < 5; kt++) {
        const int buf = kt & 1;
        f4 av;
        if (kt < 4) {
            const int kk = k0 + (kt + 1) * 32;
            stage_B(buf ^ 1, kk);
            av = *(const f4*)&X[(long)(m0 + ar) * FDIM + kk + ac4];
        }
        const float* Ab = &As[buf][0][0];
        const float* Bb = &Bs[buf][0][0];
#pragma unroll
        for (int k = 0; k < 32; k++) {
            f4 a = *(const f4*)&Ab[k * 36 + rg * 4];
            f4 b = *(const f4*)&Bb[k * 128 + cg * 4];
            acc[0] += a[0] * b;
            acc[1] += a[1] * b;
            acc[2] += a[2] * b;
            acc[3] += a[3] * b;
        }
        if (kt < 4) {
            As[(buf ^ 1)][ac4 + 0][ar] = av[0];
            As[(buf ^ 1)][ac4 + 1][ar] = av[1];
            As[(buf ^ 1)][ac4 + 2][ar] = av[2];
            As[(buf ^ 1)][ac4 + 3][ar] = av[3];
        }
        __syncthreads();
    }

#pragma unroll
    for (int r = 0; r < 4; r++)
        *(f4*)&O[(long)(m0 + rg * 4 + r) * HDIM + cg * 4] = acc[r];

    // ---- ticket: last of the 4 split-K blocks for (mat, bx) reduces ----
    __threadfence();                                   // release partials (device scope)
    if (t == 0) {
        int* ctr = (int*)(ws + WS_CTR);
        s_old = atomicAdd(&ctr[mat * 48 + blockIdx.x], 1);
    }
    __syncthreads();
    if (s_old != 3) return;
    __threadfence();                                   // acquire others' partials

    if (mat != 0) {
        // collapse fi/fj partials for rows m0..m0+31 (4096 floats = 1024 f4)
        const float* P = ws + (mat == 1 ? WS_FIP : WS_FJP);
        float* F = ws + (mat == 1 ? WS_FI : WS_FJ);
        const long base = (long)m0 * 128;
        for (int e = t; e < 1024; e += 256) {
            const long off = base + (long)e * 4;
            f4 v0 = *(const f4*)&P[off];
            f4 v1 = *(const f4*)&P[PART + off];
            f4 v2 = *(const f4*)&P[2 * PART + off];
            f4 v3 = *(const f4*)&P[3 * PART + off];
            f4 s = ((v0 + v1) + v2) + v3;              // same order as old k_row
            *(f4*)&F[off] = s;
        }
        return;
    }

    // mat==0: H1 reduce + row epilogue; wave wv handles rows m0+wv*8 .. +7
    const float* h1p = ws + WS_H1P;
    float h0[8], h1[8];
#pragma unroll
    for (int rr = 0; rr < 8; rr++) {
        const int row = m0 + wv * 8 + rr;
        const long base = (long)row * 128;
        float a0 = h1p[base + lane] + h1p[PART + base + lane]
                 + h1p[2 * PART + base + lane] + h1p[3 * PART + base + lane];
        float a1 = h1p[base + 64 + lane] + h1p[PART + base + 64 + lane]
                 + h1p[2 * PART + base + 64 + lane] + h1p[3 * PART + base + 64 + lane];
        a0 = fmaxf(a0 + b1[lane], 0.0f);
        a1 = fmaxf(a1 + b1[64 + lane], 0.0f);
        h0[rr] = gam[lane]      * (a0 - rmean[lane])      / sqrtf(rvar[lane] + 1e-5f)      + bet[lane];
        h1[rr] = gam[64 + lane] * (a1 - rmean[64 + lane]) / sqrtf(rvar[64 + lane] + 1e-5f) + bet[64 + lane];
    }

    const float b2v = b2[lane];
    float a2[8];
#pragma unroll
    for (int rr = 0; rr < 8; rr++) a2[rr] = b2v;
#pragma unroll 4
    for (int cc = 0; cc < 64; cc++) {
        const float wv0 = W2[cc * 64 + lane];
        const float wv1 = W2[(cc + 64) * 64 + lane];
#pragma unroll
        for (int rr = 0; rr < 8; rr++) {
            float hv0 = __uint_as_float(__builtin_amdgcn_readlane(__float_as_uint(h0[rr]), cc));
            float hv1 = __uint_as_float(__builtin_amdgcn_readlane(__float_as_uint(h1[rr]), cc));
            a2[rr] = fmaf(hv0, wv0, a2[rr]);
            a2[rr] = fmaf(hv1, wv1, a2[rr]);
        }
    }

    const float w30 = W3[lane * 3 + 0], w31 = W3[lane * 3 + 1], w32 = W3[lane * 3 + 2];
#pragma unroll
    for (int rr = 0; rr < 8; rr++) {
        float h2 = fmaxf(a2[rr], 0.0f);
        float x0 = h2 * w30, x1 = h2 * w31, x2 = h2 * w32;
#pragma unroll
        for (int o = 32; o > 0; o >>= 1) {
            x0 += __shfl_xor(x0, o, 64);
            x1 += __shfl_xor(x1, o, 64);
            x2 += __shfl_xor(x2, o, 64);
        }
        if (lane == 0) {
            const int row = m0 + wv * 8 + rr;
            float l0 = x0 + b3[0], l1 = x1 + b3[1], l2 = x2 + b3[2];
            float m = fmaxf(l0, fmaxf(l1, l2));
            float e0 = expf(l0 - m), e1 = expf(l1 - m), e2 = expf(l2 - m);
            float s = e0 + e1 + e2;
            float pc0 = e0 / s, pc1 = e1 / s, pc2 = e2 / s;
            out[OUT_PC + row * 3 + 0] = pc0;
            out[OUT_PC + row * 3 + 1] = pc1;
            out[OUT_PC + row * 3 + 2] = pc2;
            float net = pc0 - pc1;
            out[OUT_NET + row] = net;
            ws[WS_QC + row] = net;
            ((int*)(ws + WS_FLAG))[row] = (pc0 > pc2 ? 1 : 0) | (pc1 > pc2 ? 2 : 0);
            int sid = seq[row];
            float c0 = (sid == 6 || sid == 8 || sid == 14) ? 1.0f : 0.0f;
            float c1 = (sid == 2 || sid == 3) ? 1.0f : 0.0f;
            out[OUT_TC + row * 3 + 0] = c0;
            out[OUT_TC + row * 3 + 1] = c1;
            out[OUT_TC + row * 3 + 2] = (c0 == 0.0f && c1 == 0.0f) ? 1.0f : 0.0f;
        }
    }
}

// =========== Kernel 2: conv + pair sweep (4 rows/block) + candidate MLP ===========
__device__ __forceinline__ float mlp_eval(const float* __restrict__ fi, const float* __restrict__ fj,
                                          int gi, int gj, float D,
                                          float dv0, float dv1, float sb0, float sb1v,
                                          float b2v, float w3l, const float* w2s, int lane) {
    float fi0 = fi[(long)gi * 128 + lane];
    float fi1 = fi[(long)gi * 128 + 64 + lane];
    float fj0 = fj[(long)gj * 128 + lane];
    float fj1 = fj[(long)gj * 128 + 64 + lane];
    float h0 = fmaxf(fi0 + fj0 + D * dv0 + sb0, 0.0f);
    float h1 = fmaxf(fi1 + fj1 + D * dv1 + sb1v, 0.0f);
    float a0 = 0.0f, a1 = 0.0f;
#pragma unroll
    for (int cc = 0; cc < 64; cc++) {
        float hv0 = __uint_as_float(__builtin_amdgcn_readlane(__float_as_uint(h0), cc));
        float hv1 = __uint_as_float(__builtin_amdgcn_readlane(__float_as_uint(h1), cc));
        a0 = fmaf(hv0, w2s[cc * 64 + lane], a0);
        a1 = fmaf(hv1, w2s[(cc + 64) * 64 + lane], a1);
    }
    float x = fmaxf(a0 + a1 + b2v, 0.0f) * w3l;
#pragma unroll
    for (int o = 32; o > 0; o >>= 1) x += __shfl_xor(x, o, 64);
    return x;
}

__global__ __launch_bounds__(256) void k2(const float* __restrict__ S,
                                          const float* __restrict__ ws,
                                          const float* __restrict__ sW1,
                                          const float* __restrict__ sb1,
                                          const float* __restrict__ sW2,
                                          const float* __restrict__ sb2,
                                          const float* __restrict__ sW3,
                                          const float* __restrict__ sb3,
                                          const float* __restrict__ c1w, const float* __restrict__ c1b,
                                          const float* __restrict__ c2w, const float* __restrict__ c2b,
                                          const float* __restrict__ c3w, const float* __restrict__ c3b,
                                          float* __restrict__ out) {
    __shared__ char smem[40960];
    const int t = threadIdx.x;
    const int bi = blockIdx.x;

    if (bi < 4) {
        float* p0 = (float*)smem;
        float* p1 = p0 + 388;
        float* p2 = p1 + 16 * 386;
        const int b = bi;
        for (int j = t; j < LSEQ; j += 256) p0[j + 2] = out[OUT_NET + b * LSEQ + j];
        if (t < 2) { p0[t] = 0.0f; p0[LSEQ + 2 + t] = 0.0f; }
        if (t < 16) { p1[t * 386] = 0.0f; p1[t * 386 + 385] = 0.0f; }
        if (t < 8)  { p2[t * 386] = 0.0f; p2[t * 386 + 385] = 0.0f; }
        __syncthreads();
        for (int pos = t; pos < LSEQ; pos += 256) {
#pragma unroll
            for (int o = 0; o < 16; o++) {
                float acc = c1b[o];
#pragma unroll
                for (int k = 0; k < 5; k++) acc = fmaf(p0[pos + k], c1w[o * 5 + k], acc);
                p1[o * 386 + pos + 1] = fmaxf(acc, 0.0f);
            }
        }
        __syncthreads();
        for (int pos = t; pos < LSEQ; pos += 256) {
#pragma unroll
            for (int o = 0; o < 8; o++) {
                float acc = c2b[o];
                for (int i = 0; i < 16; i++)
#pragma unroll
                    for (int k = 0; k < 3; k++)
                        acc = fmaf(p1[i * 386 + pos + k], c2w[(o * 16 + i) * 3 + k], acc);
                p2[o * 386 + pos + 1] = fmaxf(acc, 0.0f);
            }
        }
        __syncthreads();
        for (int pos = t; pos < LSEQ; pos += 256) {
            float acc = c3b[0];
            for (int i = 0; i < 8; i++)
#pragma unroll
                for (int k = 0; k < 3; k++)
                    acc = fmaf(p2[i * 386 + pos + k], c3w[i * 3 + k], acc);
            out[OUT_POT + b * LSEQ + pos] = acc;
        }
        return;
    }

    float* sx = (float*)smem;                         // 384
    float* sy = sx + 384;
    float* sz = sy + 384;
    float* sq = sz + 384;                             // @1152
    unsigned int* clist = (unsigned int*)(sx + 1536); // 384 entries, bytes 6144..7680
    unsigned char* sf = (unsigned char*)(smem + 7680);
    float* red = (float*)(smem + 8064);
    int* cntL = (int*)(smem + 8080);
    int* w2flag = (int*)(smem + 8084);
    float* w2s = (float*)(smem + 8192);               // 32KB

    const float* qc = ws + WS_QC;
    const int* flags = (const int*)(ws + WS_FLAG);
    const float* fi = ws + WS_FI;
    const float* fj = ws + WS_FJ;

    const int rowblk = bi - 4;            // 0..383
    const int b = rowblk / 96;
    const int i0 = (rowblk % 96) * 4;

    for (int j = t; j < LSEQ; j += 256) {
        int g = b * LSEQ + j;
        sx[j] = S[g * 3 + 0];
        sy[j] = S[g * 3 + 1];
        sz[j] = S[g * 3 + 2];
        sq[j] = qc[g];
        sf[j] = (unsigned char)flags[g];
    }
    if (t == 0) *w2flag = 0;
    __syncthreads();

    const int lane = t & 63, w = t >> 6;
    const float* dvec = sW1 + 1280 * 128;
    const float dv0 = dvec[lane], dv1 = dvec[lane + 64];
    const float sb0 = sb1[lane], sb1v = sb1[lane + 64];
    const float w3l = sW3[lane];
    const float b2v = sb2[lane];
    const float b3v = sb3[0];

    float esum = 0.0f;     // accumulated across all 4 rows, reduced once at end

    for (int r = 0; r < 4; r++) {
        const int i = i0 + r;
        const int grow = b * LSEQ + i;
        if (t == 0) *cntL = 0;
        __syncthreads();

        const float six = sx[i], siy = sy[i], siz = sz[i], qi = sq[i];
        const int fli = sf[i];
        const bool posi = (fli & 1) != 0, negi = (fli & 2) != 0;
        float* mrow = out + OUT_MASK + (long)grow * LSEQ;

        for (int j = t; j < LSEQ; j += 256) {
            float dx = __fsub_rn(six, sx[j]);
            float dy = __fsub_rn(siy, sy[j]);
            float dz = __fsub_rn(siz, sz[j]);
            float d2 = __fadd_rn(__fadd_rn(__fmul_rn(dx, dx), __fmul_rn(dy, dy)), __fmul_rn(dz, dz));
            d2 = __fadd_rn(d2, 1e-12f);
            float D = __fsqrt_rn(d2);
            mrow[j] = 0.0f;
            if (j > i && D < 15.0f && D > 0.0f) {
                float num = __fmul_rn(__fmul_rn(332.0f, qi), sq[j]);
                float den = __fmul_rn(__fmul_rn(20.0f, D), D);
                esum += __fdiv_rn(num, den);
            }
            int flj = sf[j];
            bool near = (D < 4.0f);
            bool need1 = near && posi && ((flj & 2) != 0);
            bool need2 = near && negi && ((flj & 1) != 0);
            if (need1 || need2) {
                int p = atomicAdd(cntL, 1);
                clist[p] = (unsigned int)j | (need1 ? 512u : 0u) | (need2 ? 1024u : 0u);
            }
        }
        __syncthreads();                  // clist complete

        int nc = *cntL;                   // uniform
        if (nc > 0) {
            if (!*w2flag) {               // lazy one-time w2s stage (uniform branch)
                for (int idx = t; idx < 2048; idx += 256)
                    ((float4*)w2s)[idx] = ((const float4*)sW2)[idx];
                __syncthreads();
                if (t == 0) *w2flag = 1;
            }
            for (int c = w; c < nc; c += 4) {
                unsigned int e = clist[c];
                int j = (int)(e & 511u);
                bool need1 = (e & 512u) != 0, need2 = (e & 1024u) != 0;
                float dx = __fsub_rn(six, sx[j]);
                float dy = __fsub_rn(siy, sy[j]);
                float dz = __fsub_rn(siz, sz[j]);
                float d2 = __fadd_rn(__fadd_rn(__fmul_rn(dx, dx), __fmul_rn(dy, dy)), __fmul_rn(dz, dz));
                d2 = __fadd_rn(d2, 1e-12f);
                float D = __fsqrt_rn(d2);
                int gi = grow, gj = b * LSEQ + j;
                bool hit = false;
                if (need1) {
                    float x = mlp_eval(fi, fj, gi, gj, D, dv0, dv1, sb0, sb1v, b2v, w3l, w2s, lane);
                    hit = (x + b3v) > 0.0f;
                }
                if (!hit && need2) {
                    float x = mlp_eval(fi, fj, gj, gi, D, dv0, dv1, sb0, sb1v, b2v, w3l, w2s, lane);
                    hit = (x + b3v) > 0.0f;
                }
                if (hit && lane == 0) mrow[j] = 1.0f;
            }
        }
        __syncthreads();                  // clist/cnt reuse safety
    }

    // block-wide energy reduce, one atomicAdd per block
#pragma unroll
    for (int o = 32; o > 0; o >>= 1) esum += __shfl_xor(esum, o, 64);
    if (lane == 0) red[w] = esum;
    __syncthreads();
    if (t == 0) {
        float s = red[0] + red[1] + red[2] + red[3];
        atomicAdd(&out[OUT_EN + b], s);
    }
}

extern "C" void kernel_launch(void* const* d_in, const int* in_sizes, int n_in,
                              void* d_out, int out_size, void* d_ws, size_t ws_size,
                              hipStream_t stream) {
    const float* X     = (const float*)d_in[0];
    const int*   seq   = (const int*)d_in[1];
    const float* S     = (const float*)d_in[2];
    const float* W1    = (const float*)d_in[3];
    const float* b1    = (const float*)d_in[4];
    const float* gam   = (const float*)d_in[5];
    const float* bet   = (const float*)d_in[6];
    const float* rmean = (const float*)d_in[7];
    const float* rvar  = (const float*)d_in[8];
    const float* W2    = (const float*)d_in[9];
    const float* b2    = (const float*)d_in[10];
    const float* W3    = (const float*)d_in[11];
    const float* b3    = (const float*)d_in[12];
    const float* sW1   = (const float*)d_in[13];
    const float* sb1   = (const float*)d_in[14];
    const float* sW2   = (const float*)d_in[15];
    const float* sb2   = (const float*)d_in[16];
    const float* sW3   = (const float*)d_in[17];
    const float* sb3   = (const float*)d_in[18];
    const float* c1w   = (const float*)d_in[19];
    const float* c1b   = (const float*)d_in[20];
    const float* c2w   = (const float*)d_in[21];
    const float* c2b   = (const float*)d_in[22];
    const float* c3w   = (const float*)d_in[23];
    const float* c3b   = (const float*)d_in[24];

    float* out = (float*)d_out;
    float* ws  = (float*)d_ws;

    // zero the 144 ticket counters (tiny, graph-capturable)
    hipMemsetAsync(ws + WS_CTR, 0, 144 * sizeof(int), stream);

    hipLaunchKernelGGL(k_gemm, dim3(48, 12), dim3(256), 0, stream,
                       X, W1, sW1, b1, gam, bet, rmean, rvar, W2, b2, W3, b3, seq, ws, out);
    hipLaunchKernelGGL(k2, dim3(388), dim3(256), 0, stream,
                       S, ws, sW1, sb1, sW2, sb2, sW3, sb3,
                       c1w, c1b, c2w, c2b, c3w, c3b, out);
}

// Round 5
// 154.275 us; speedup vs baseline: 1.4873x; 1.4873x over previous
//
#include <hip/hip_runtime.h>

#define LSEQ 384
#define NROWS 1536      // B*L
#define FDIM 640
#define HDIM 128
#define PART 196608     // 1536*128

// ws layout (float indices)
#define WS_H1P 0                 // 4 x PART (H1 split-K partials)
#define WS_FIP (4*PART)          // 4 x PART
#define WS_FJP (8*PART)          // 4 x PART
#define WS_FI  (12*PART)         // final fi
#define WS_FJ  (13*PART)         // final fj
#define WS_QC  (14*PART)
#define WS_FLAG (WS_QC + NROWS)  // int[1536]

// out layout (float indices)
#define OUT_PC    0
#define OUT_TC    4608
#define OUT_NET   9216
#define OUT_POT   10752
#define OUT_MASK  12288
#define OUT_EN    602112

typedef float f4 __attribute__((ext_vector_type(4)));

__device__ __forceinline__ void gl16(const float* g, float* l) {
    __builtin_amdgcn_global_load_lds((const __attribute__((address_space(1))) float*)g,
                                     (__attribute__((address_space(3))) float*)l, 16, 0, 0);
}

// =========== Kernel 1: split-K=4 GEMM, BM=32 BN=128 BK=32, acc 4x4 (round-3) ===========
// grid (48, 12): bx = m-tile (32 rows); by: mat = by>>2 (0=H1,1=fi,2=fj), kz = by&3.
// NOTE: no device-scope fences here — cross-block visibility is provided by the
// kernel boundary (one flush for the whole device). Round-4's in-kernel ticket
// (2 x __threadfence per block) cost ~80us in L2 writeback/invalidate traffic.
__global__ __launch_bounds__(256) void k_gemm(const float* __restrict__ X,
                                              const float* __restrict__ W1,
                                              const float* __restrict__ sW1,
                                              float* __restrict__ ws,
                                              float* __restrict__ out) {
    __shared__ __align__(16) float As[2][32][36];    // [buf][k][m] pad 36 (f4-aligned rows)
    __shared__ __align__(16) float Bs[2][32][128];   // [buf][k][n] 16KB each

    const int t = threadIdx.x;
    if (blockIdx.x == 0 && blockIdx.y == 0 && t < 4)
        out[OUT_EN + t] = 0.0f;        // energy zero (k2 atomicAdds later)

    const int m0 = blockIdx.x * 32;
    const int by = blockIdx.y;
    const int mat = by >> 2, kz = by & 3;
    const float* W = (mat == 0) ? W1 : (mat == 1 ? sW1 : sW1 + FDIM * HDIM);
    float* O = ws + (mat == 0 ? WS_H1P : (mat == 1 ? WS_FIP : WS_FJP)) + kz * PART;
    const int k0 = kz * 160;            // 5 iterations of BK=32

    const int lane = t & 63, wv = t >> 6;
    const int rg = t >> 5;              // 0..7 : row group (4 rows)
    const int cg = t & 31;              // 0..31: col group (4 cols)
    const int ar = t >> 3, ac4 = (t & 7) * 4;   // A stage: row 0..31, col4 0..28

    // stage B tile (32x128 = 16KB, contiguous in W) into Bs[buf]; 16 chunks of 1024B
    auto stage_B = [&](int buf, int kk) {
        const float* src = W + (long)kk * HDIM;
        float* dst = &Bs[buf][0][0];
#pragma unroll
        for (int i = 0; i < 4; i++) {
            const int c = wv * 4 + i;               // wave-uniform chunk id
            gl16(src + c * 256 + lane * 4, dst + c * 256);
        }
    };

    f4 acc[4];
    acc[0] = acc[1] = acc[2] = acc[3] = (f4){0.f, 0.f, 0.f, 0.f};

    // prologue: tile 0
    stage_B(0, k0);
    {
        f4 av = *(const f4*)&X[(long)(m0 + ar) * FDIM + k0 + ac4];
        As[0][ac4 + 0][ar] = av[0];
        As[0][ac4 + 1][ar] = av[1];
        As[0][ac4 + 2][ar] = av[2];
        As[0][ac4 + 3][ar] = av[3];
    }
    __syncthreads();

    for (int kt = 0; kt < 5; kt++) {
        const int buf = kt & 1;
        f4 av;
        if (kt < 4) {
            const int kk = k0 + (kt + 1) * 32;
            stage_B(buf ^ 1, kk);                           // async over compute
            av = *(const f4*)&X[(long)(m0 + ar) * FDIM + kk + ac4];
        }
        const float* Ab = &As[buf][0][0];
        const float* Bb = &Bs[buf][0][0];
#pragma unroll
        for (int k = 0; k < 32; k++) {
            f4 a = *(const f4*)&Ab[k * 36 + rg * 4];        // 2-addr broadcast
            f4 b = *(const f4*)&Bb[k * 128 + cg * 4];       // 512B span, 2-way bcast
            acc[0] += a[0] * b;
            acc[1] += a[1] * b;
            acc[2] += a[2] * b;
            acc[3] += a[3] * b;
        }
        if (kt < 4) {
            As[(buf ^ 1)][ac4 + 0][ar] = av[0];
            As[(buf ^ 1)][ac4 + 1][ar] = av[1];
            As[(buf ^ 1)][ac4 + 2][ar] = av[2];
            As[(buf ^ 1)][ac4 + 3][ar] = av[3];
        }
        __syncthreads();
    }

#pragma unroll
    for (int r = 0; r < 4; r++)
        *(f4*)&O[(long)(m0 + rg * 4 + r) * HDIM + cg * 4] = acc[r];
}

// =========== Kernel 2: partial reduce + row epilogue (round-3 proven) ===========
__global__ __launch_bounds__(256) void k_row(float* __restrict__ ws,
                                             const float* __restrict__ b1,
                                             const float* __restrict__ gam,
                                             const float* __restrict__ bet,
                                             const float* __restrict__ rmean,
                                             const float* __restrict__ rvar,
                                             const float* __restrict__ W2,
                                             const float* __restrict__ b2,
                                             const float* __restrict__ W3,
                                             const float* __restrict__ b3,
                                             const int* __restrict__ seq,
                                             float* __restrict__ out) {
    const int t = threadIdx.x, w = t >> 6, lane = t & 63;
    const int row = blockIdx.x * 4 + w;
    const long base = (long)row * 128;
    const float* h1p = ws + WS_H1P;
    const float* fip = ws + WS_FIP;
    const float* fjp = ws + WS_FJP;

    // fi/fj partial collapse (2 cols per lane)
    {
        float fi0 = fip[base + lane] + fip[PART + base + lane]
                  + fip[2 * PART + base + lane] + fip[3 * PART + base + lane];
        float fi1 = fip[base + 64 + lane] + fip[PART + base + 64 + lane]
                  + fip[2 * PART + base + 64 + lane] + fip[3 * PART + base + 64 + lane];
        float fj0 = fjp[base + lane] + fjp[PART + base + lane]
                  + fjp[2 * PART + base + lane] + fjp[3 * PART + base + lane];
        float fj1 = fjp[base + 64 + lane] + fjp[PART + base + 64 + lane]
                  + fjp[2 * PART + base + 64 + lane] + fjp[3 * PART + base + 64 + lane];
        ws[WS_FI + base + lane]      = fi0;
        ws[WS_FI + base + 64 + lane] = fi1;
        ws[WS_FJ + base + lane]      = fj0;
        ws[WS_FJ + base + 64 + lane] = fj1;
    }

    // H1 reduce + bias/relu/BN
    float h0 = h1p[base + lane] + h1p[PART + base + lane]
             + h1p[2 * PART + base + lane] + h1p[3 * PART + base + lane];
    float h1 = h1p[base + 64 + lane] + h1p[PART + base + 64 + lane]
             + h1p[2 * PART + base + 64 + lane] + h1p[3 * PART + base + 64 + lane];
    h0 = fmaxf(h0 + b1[lane], 0.0f);
    h1 = fmaxf(h1 + b1[64 + lane], 0.0f);
    h0 = gam[lane]      * (h0 - rmean[lane])      / sqrtf(rvar[lane] + 1e-5f)      + bet[lane];
    h1 = gam[64 + lane] * (h1 - rmean[64 + lane]) / sqrtf(rvar[64 + lane] + 1e-5f) + bet[64 + lane];

    // W2: out channel = lane; inputs broadcast via readlane
    float acc = b2[lane];
#pragma unroll
    for (int cc = 0; cc < 64; cc++) {
        float wv0 = W2[cc * 64 + lane];
        float wv1 = W2[(cc + 64) * 64 + lane];
        float hv0 = __uint_as_float(__builtin_amdgcn_readlane(__float_as_uint(h0), cc));
        float hv1 = __uint_as_float(__builtin_amdgcn_readlane(__float_as_uint(h1), cc));
        acc = fmaf(hv0, wv0, acc);
        acc = fmaf(hv1, wv1, acc);
    }
    float h2 = fmaxf(acc, 0.0f);
    float x0 = h2 * W3[lane * 3 + 0];
    float x1 = h2 * W3[lane * 3 + 1];
    float x2 = h2 * W3[lane * 3 + 2];
#pragma unroll
    for (int o = 32; o > 0; o >>= 1) {
        x0 += __shfl_xor(x0, o, 64);
        x1 += __shfl_xor(x1, o, 64);
        x2 += __shfl_xor(x2, o, 64);
    }
    if (lane == 0) {
        float l0 = x0 + b3[0], l1 = x1 + b3[1], l2 = x2 + b3[2];
        float m = fmaxf(l0, fmaxf(l1, l2));
        float e0 = expf(l0 - m), e1 = expf(l1 - m), e2 = expf(l2 - m);
        float s = e0 + e1 + e2;
        float pc0 = e0 / s, pc1 = e1 / s, pc2 = e2 / s;
        out[OUT_PC + row * 3 + 0] = pc0;
        out[OUT_PC + row * 3 + 1] = pc1;
        out[OUT_PC + row * 3 + 2] = pc2;
        float net = pc0 - pc1;
        out[OUT_NET + row] = net;
        ws[WS_QC + row] = net;
        ((int*)(ws + WS_FLAG))[row] = (pc0 > pc2 ? 1 : 0) | (pc1 > pc2 ? 2 : 0);
        int sid = seq[row];
        float c0 = (sid == 6 || sid == 8 || sid == 14) ? 1.0f : 0.0f;
        float c1 = (sid == 2 || sid == 3) ? 1.0f : 0.0f;
        out[OUT_TC + row * 3 + 0] = c0;
        out[OUT_TC + row * 3 + 1] = c1;
        out[OUT_TC + row * 3 + 2] = (c0 == 0.0f && c1 == 0.0f) ? 1.0f : 0.0f;
    }
}

// =========== Kernel 3: conv + pair sweep (4 rows/block, round-4 proven) ===========
__device__ __forceinline__ float mlp_eval(const float* __restrict__ fi, const float* __restrict__ fj,
                                          int gi, int gj, float D,
                                          float dv0, float dv1, float sb0, float sb1v,
                                          float b2v, float w3l, const float* w2s, int lane) {
    float fi0 = fi[(long)gi * 128 + lane];
    float fi1 = fi[(long)gi * 128 + 64 + lane];
    float fj0 = fj[(long)gj * 128 + lane];
    float fj1 = fj[(long)gj * 128 + 64 + lane];
    float h0 = fmaxf(fi0 + fj0 + D * dv0 + sb0, 0.0f);
    float h1 = fmaxf(fi1 + fj1 + D * dv1 + sb1v, 0.0f);
    float a0 = 0.0f, a1 = 0.0f;
#pragma unroll
    for (int cc = 0; cc < 64; cc++) {
        float hv0 = __uint_as_float(__builtin_amdgcn_readlane(__float_as_uint(h0), cc));
        float hv1 = __uint_as_float(__builtin_amdgcn_readlane(__float_as_uint(h1), cc));
        a0 = fmaf(hv0, w2s[cc * 64 + lane], a0);
        a1 = fmaf(hv1, w2s[(cc + 64) * 64 + lane], a1);
    }
    float x = fmaxf(a0 + a1 + b2v, 0.0f) * w3l;
#pragma unroll
    for (int o = 32; o > 0; o >>= 1) x += __shfl_xor(x, o, 64);
    return x;
}

__global__ __launch_bounds__(256) void k2(const float* __restrict__ S,
                                          const float* __restrict__ ws,
                                          const float* __restrict__ sW1,
                                          const float* __restrict__ sb1,
                                          const float* __restrict__ sW2,
                                          const float* __restrict__ sb2,
                                          const float* __restrict__ sW3,
                                          const float* __restrict__ sb3,
                                          const float* __restrict__ c1w, const float* __restrict__ c1b,
                                          const float* __restrict__ c2w, const float* __restrict__ c2b,
                                          const float* __restrict__ c3w, const float* __restrict__ c3b,
                                          float* __restrict__ out) {
    __shared__ char smem[40960];
    const int t = threadIdx.x;
    const int bi = blockIdx.x;

    if (bi < 4) {
        float* p0 = (float*)smem;
        float* p1 = p0 + 388;
        float* p2 = p1 + 16 * 386;
        const int b = bi;
        for (int j = t; j < LSEQ; j += 256) p0[j + 2] = out[OUT_NET + b * LSEQ + j];
        if (t < 2) { p0[t] = 0.0f; p0[LSEQ + 2 + t] = 0.0f; }
        if (t < 16) { p1[t * 386] = 0.0f; p1[t * 386 + 385] = 0.0f; }
        if (t < 8)  { p2[t * 386] = 0.0f; p2[t * 386 + 385] = 0.0f; }
        __syncthreads();
        for (int pos = t; pos < LSEQ; pos += 256) {
#pragma unroll
            for (int o = 0; o < 16; o++) {
                float acc = c1b[o];
#pragma unroll
                for (int k = 0; k < 5; k++) acc = fmaf(p0[pos + k], c1w[o * 5 + k], acc);
                p1[o * 386 + pos + 1] = fmaxf(acc, 0.0f);
            }
        }
        __syncthreads();
        for (int pos = t; pos < LSEQ; pos += 256) {
#pragma unroll
            for (int o = 0; o < 8; o++) {
                float acc = c2b[o];
                for (int i = 0; i < 16; i++)
#pragma unroll
                    for (int k = 0; k < 3; k++)
                        acc = fmaf(p1[i * 386 + pos + k], c2w[(o * 16 + i) * 3 + k], acc);
                p2[o * 386 + pos + 1] = fmaxf(acc, 0.0f);
            }
        }
        __syncthreads();
        for (int pos = t; pos < LSEQ; pos += 256) {
            float acc = c3b[0];
            for (int i = 0; i < 8; i++)
#pragma unroll
                for (int k = 0; k < 3; k++)
                    acc = fmaf(p2[i * 386 + pos + k], c3w[i * 3 + k], acc);
            out[OUT_POT + b * LSEQ + pos] = acc;
        }
        return;
    }

    float* sx = (float*)smem;                         // 384
    float* sy = sx + 384;
    float* sz = sy + 384;
    float* sq = sz + 384;                             // @1152
    unsigned int* clist = (unsigned int*)(sx + 1536); // 384 entries, bytes 6144..7680
    unsigned char* sf = (unsigned char*)(smem + 7680);
    float* red = (float*)(smem + 8064);
    int* cntL = (int*)(smem + 8080);
    int* w2flag = (int*)(smem + 8084);
    float* w2s = (float*)(smem + 8192);               // 32KB

    const float* qc = ws + WS_QC;
    const int* flags = (const int*)(ws + WS_FLAG);
    const float* fi = ws + WS_FI;
    const float* fj = ws + WS_FJ;

    const int rowblk = bi - 4;            // 0..383
    const int b = rowblk / 96;
    const int i0 = (rowblk % 96) * 4;

    for (int j = t; j < LSEQ; j += 256) {
        int g = b * LSEQ + j;
        sx[j] = S[g * 3 + 0];
        sy[j] = S[g * 3 + 1];
        sz[j] = S[g * 3 + 2];
        sq[j] = qc[g];
        sf[j] = (unsigned char)flags[g];
    }
    if (t == 0) *w2flag = 0;
    __syncthreads();

    const int lane = t & 63, w = t >> 6;
    const float* dvec = sW1 + 1280 * 128;
    const float dv0 = dvec[lane], dv1 = dvec[lane + 64];
    const float sb0 = sb1[lane], sb1v = sb1[lane + 64];
    const float w3l = sW3[lane];
    const float b2v = sb2[lane];
    const float b3v = sb3[0];

    float esum = 0.0f;     // accumulated across all 4 rows, reduced once at end

    for (int r = 0; r < 4; r++) {
        const int i = i0 + r;
        const int grow = b * LSEQ + i;
        if (t == 0) *cntL = 0;
        __syncthreads();

        const float six = sx[i], siy = sy[i], siz = sz[i], qi = sq[i];
        const int fli = sf[i];
        const bool posi = (fli & 1) != 0, negi = (fli & 2) != 0;
        float* mrow = out + OUT_MASK + (long)grow * LSEQ;

        for (int j = t; j < LSEQ; j += 256) {
            float dx = __fsub_rn(six, sx[j]);
            float dy = __fsub_rn(siy, sy[j]);
            float dz = __fsub_rn(siz, sz[j]);
            float d2 = __fadd_rn(__fadd_rn(__fmul_rn(dx, dx), __fmul_rn(dy, dy)), __fmul_rn(dz, dz));
            d2 = __fadd_rn(d2, 1e-12f);
            float D = __fsqrt_rn(d2);
            mrow[j] = 0.0f;
            if (j > i && D < 15.0f && D > 0.0f) {
                float num = __fmul_rn(__fmul_rn(332.0f, qi), sq[j]);
                float den = __fmul_rn(__fmul_rn(20.0f, D), D);
                esum += __fdiv_rn(num, den);
            }
            int flj = sf[j];
            bool near = (D < 4.0f);
            bool need1 = near && posi && ((flj & 2) != 0);
            bool need2 = near && negi && ((flj & 1) != 0);
            if (need1 || need2) {
                int p = atomicAdd(cntL, 1);
                clist[p] = (unsigned int)j | (need1 ? 512u : 0u) | (need2 ? 1024u : 0u);
            }
        }
        __syncthreads();                  // clist complete

        int nc = *cntL;                   // uniform
        if (nc > 0) {
            if (!*w2flag) {               // lazy one-time w2s stage (uniform branch)
                for (int idx = t; idx < 2048; idx += 256)
                    ((float4*)w2s)[idx] = ((const float4*)sW2)[idx];
                __syncthreads();
                if (t == 0) *w2flag = 1;
            }
            for (int c = w; c < nc; c += 4) {
                unsigned int e = clist[c];
                int j = (int)(e & 511u);
                bool need1 = (e & 512u) != 0, need2 = (e & 1024u) != 0;
                float dx = __fsub_rn(six, sx[j]);
                float dy = __fsub_rn(siy, sy[j]);
                float dz = __fsub_rn(siz, sz[j]);
                float d2 = __fadd_rn(__fadd_rn(__fmul_rn(dx, dx), __fmul_rn(dy, dy)), __fmul_rn(dz, dz));
                d2 = __fadd_rn(d2, 1e-12f);
                float D = __fsqrt_rn(d2);
                int gi = grow, gj = b * LSEQ + j;
                bool hit = false;
                if (need1) {
                    float x = mlp_eval(fi, fj, gi, gj, D, dv0, dv1, sb0, sb1v, b2v, w3l, w2s, lane);
                    hit = (x + b3v) > 0.0f;
                }
                if (!hit && need2) {
                    float x = mlp_eval(fi, fj, gj, gi, D, dv0, dv1, sb0, sb1v, b2v, w3l, w2s, lane);
                    hit = (x + b3v) > 0.0f;
                }
                if (hit && lane == 0) mrow[j] = 1.0f;
            }
        }
        __syncthreads();                  // clist/cnt reuse safety
    }

    // block-wide energy reduce, one atomicAdd per block
#pragma unroll
    for (int o = 32; o > 0; o >>= 1) esum += __shfl_xor(esum, o, 64);
    if (lane == 0) red[w] = esum;
    __syncthreads();
    if (t == 0) {
        float s = red[0] + red[1] + red[2] + red[3];
        atomicAdd(&out[OUT_EN + b], s);
    }
}

extern "C" void kernel_launch(void* const* d_in, const int* in_sizes, int n_in,
                              void* d_out, int out_size, void* d_ws, size_t ws_size,
                              hipStream_t stream) {
    const float* X     = (const float*)d_in[0];
    const int*   seq   = (const int*)d_in[1];
    const float* S     = (const float*)d_in[2];
    const float* W1    = (const float*)d_in[3];
    const float* b1    = (const float*)d_in[4];
    const float* gam   = (const float*)d_in[5];
    const float* bet   = (const float*)d_in[6];
    const float* rmean = (const float*)d_in[7];
    const float* rvar  = (const float*)d_in[8];
    const float* W2    = (const float*)d_in[9];
    const float* b2    = (const float*)d_in[10];
    const float* W3    = (const float*)d_in[11];
    const float* b3    = (const float*)d_in[12];
    const float* sW1   = (const float*)d_in[13];
    const float* sb1   = (const float*)d_in[14];
    const float* sW2   = (const float*)d_in[15];
    const float* sb2   = (const float*)d_in[16];
    const float* sW3   = (const float*)d_in[17];
    const float* sb3   = (const float*)d_in[18];
    const float* c1w   = (const float*)d_in[19];
    const float* c1b   = (const float*)d_in[20];
    const float* c2w   = (const float*)d_in[21];
    const float* c2b   = (const float*)d_in[22];
    const float* c3w   = (const float*)d_in[23];
    const float* c3b   = (const float*)d_in[24];

    float* out = (float*)d_out;
    float* ws  = (float*)d_ws;

    hipLaunchKernelGGL(k_gemm, dim3(48, 12), dim3(256), 0, stream, X, W1, sW1, ws, out);
    hipLaunchKernelGGL(k_row, dim3(384), dim3(256), 0, stream,
                       ws, b1, gam, bet, rmean, rvar, W2, b2, W3, b3, seq, out);
    hipLaunchKernelGGL(k2, dim3(388), dim3(256), 0, stream,
                       S, ws, sW1, sb1, sW2, sb2, sW3, sb3,
                       c1w, c1b, c2w, c2b, c3w, c3b, out);
}